// Round 2
// baseline (630.241 us; speedup 1.0000x reference)
//
#include <hip/hip_runtime.h>

// out[c,i,j] = one_hot[i,c]   (c<4)   — row broadcast (1 scalar per block)
// out[c,i,j] = one_hot[j,c-4] (c>=4)  — column broadcast (stage column via LDS)
// L=4096, one_hot: [L,4] f32, out: [8,L,L] f32 (512 MiB -> pure write-BW bound)

constexpr int L  = 4096;
constexpr int NB = 4;

__global__ __launch_bounds__(256) void seq_embed(const float4* __restrict__ oh4,
                                                 float* __restrict__ out) {
    __shared__ float col[L];           // 16 KiB: one staged column (bottom blocks)
    const int row = blockIdx.x;        // (channel, i)
    const int c   = row >> 12;
    const int i   = row & (L - 1);
    const int t   = threadIdx.x;
    float4* __restrict__ orow =
        reinterpret_cast<float4*>(out) + (size_t)row * (L / 4);

    if (c < NB) {
        // whole row = one scalar
        const float v = reinterpret_cast<const float*>(oh4)[i * NB + c];
        const float4 v4 = make_float4(v, v, v, v);
#pragma unroll
        for (int k = 0; k < 4; ++k)
            orow[t + 256 * k] = v4;                  // coalesced float4 stores
    } else {
        const int cc = c - NB;
        // stage column cc of one_hot with COALESCED float4 loads:
        // lane t loads position p's full 4-float row (16 B), keeps component cc
#pragma unroll
        for (int k = 0; k < 16; ++k) {
            const int p = t + 256 * k;
            const float4 v = oh4[p];                 // 16 B/lane, lane-consecutive
            const float* vf = reinterpret_cast<const float*>(&v);
            col[p] = vf[cc];                         // stride-1 LDS: conflict-free
        }
        __syncthreads();
        const float4* col4 = reinterpret_cast<const float4*>(col);
#pragma unroll
        for (int k = 0; k < 4; ++k) {
            const int j4 = t + 256 * k;
            orow[j4] = col4[j4];                     // ds_read_b128 + coalesced store
        }
    }
}

extern "C" void kernel_launch(void* const* d_in, const int* in_sizes, int n_in,
                              void* d_out, int out_size, void* d_ws, size_t ws_size,
                              hipStream_t stream) {
    const float4* oh4 = (const float4*)d_in[0];
    float* out = (float*)d_out;
    seq_embed<<<8 * L, 256, 0, stream>>>(oh4, out);
}

// Round 3
// 517.815 us; speedup vs baseline: 1.2171x; 1.2171x over previous
//
#include <hip/hip_runtime.h>

// out[c,i,j] = one_hot[i,c]   (c<4)   — row broadcast
// out[c,i,j] = one_hot[j,c-4] (c>=4)  — column broadcast
// L=4096, one_hot [L,4] f32, out [8,L,L] f32 (512 MiB, pure write-BW bound).
//
// R2 lesson: 32768 short blocks (4 stores/thread) only reached ~2.2 TB/s while
// rocclr fillBuffer reaches 6.2 TB/s with long-lived grid-stride waves.
// => 2048 blocks (8/CU), 16 rows/block, 64 float4 stores/thread from registers.

constexpr int L   = 4096;
constexpr int NB  = 4;
constexpr int RPB = 16;                 // rows per block
constexpr int BPC = L / RPB;            // blocks per channel = 256

__global__ __launch_bounds__(256) void seq_embed(const float4* __restrict__ oh4,
                                                 float* __restrict__ out) {
    __shared__ float col[L];            // 16 KiB (bottom channels only)
    const int blk  = blockIdx.x;        // 0..2047
    const int c    = blk >> 8;          // blk / BPC : channel 0..7
    const int row0 = (blk & (BPC - 1)) * RPB;
    const int t    = threadIdx.x;
    float4* __restrict__ out4 = reinterpret_cast<float4*>(out);

    if (c < NB) {
        const float* oh = reinterpret_cast<const float*>(oh4);
        // 16 wave-uniform scalar loads (i uniform per iteration -> s_load)
        float v[RPB];
#pragma unroll
        for (int r = 0; r < RPB; ++r) v[r] = oh[(row0 + r) * NB + c];
#pragma unroll
        for (int r = 0; r < RPB; ++r) {
            float4* orow = out4 + (size_t)(c * L + row0 + r) * (L / 4);
            const float4 v4 = make_float4(v[r], v[r], v[r], v[r]);
#pragma unroll
            for (int k = 0; k < 4; ++k)
                orow[t + 256 * k] = v4;          // coalesced dwordx4 stores
        }
    } else {
        const int cc = c - NB;
        // stage column cc once per block with coalesced float4 loads
#pragma unroll
        for (int k = 0; k < 16; ++k) {
            const int p = t + 256 * k;
            const float4 w = oh4[p];             // 16 B/lane, lane-consecutive
            const float* wf = reinterpret_cast<const float*>(&w);
            col[p] = wf[cc];
        }
        __syncthreads();
        const float4* col4 = reinterpret_cast<const float4*>(col);
        float4 v[4];
#pragma unroll
        for (int k = 0; k < 4; ++k) v[k] = col4[t + 256 * k];  // 4 ds_read_b128
#pragma unroll
        for (int r = 0; r < RPB; ++r) {
            float4* orow = out4 + (size_t)(c * L + row0 + r) * (L / 4);
#pragma unroll
            for (int k = 0; k < 4; ++k)
                orow[t + 256 * k] = v[k];        // 64 stores/thread total
        }
    }
}

extern "C" void kernel_launch(void* const* d_in, const int* in_sizes, int n_in,
                              void* d_out, int out_size, void* d_ws, size_t ws_size,
                              hipStream_t stream) {
    const float4* oh4 = (const float4*)d_in[0];
    float* out = (float*)d_out;
    seq_embed<<<8 * BPC, 256, 0, stream>>>(oh4, out);
}

// Round 5
// 514.421 us; speedup vs baseline: 1.2251x; 1.0066x over previous
//
#include <hip/hip_runtime.h>

// out[c,i,j] = one_hot[i,c]   (c<4)   — row broadcast
// out[c,i,j] = one_hot[j,c-4] (c>=4)  — column broadcast
// L=4096, one_hot [L,4] f32, out [8,L,L] f32 (512 MiB, pure write-BW bound).
//
// R3: 2048 long-lived blocks, 64 float4 stores/thread -> 630->518 us.
// R5: nontemporal stores via native ext_vector float4 (HIP_vector_type struct
//     is rejected by the builtin). Streaming 512 MiB (16x L2) with write-back
//     stores churns L2 dirty evictions; nt streams past L2 like a fill.

typedef float f32x4 __attribute__((ext_vector_type(4)));

constexpr int L   = 4096;
constexpr int NB  = 4;
constexpr int RPB = 16;                 // rows per block
constexpr int BPC = L / RPB;            // blocks per channel = 256

__global__ __launch_bounds__(256) void seq_embed(const f32x4* __restrict__ oh4,
                                                 float* __restrict__ out) {
    __shared__ float col[L];            // 16 KiB (bottom channels only)
    const int blk  = blockIdx.x;        // 0..2047
    const int c    = blk >> 8;          // channel 0..7
    const int row0 = (blk & (BPC - 1)) * RPB;
    const int t    = threadIdx.x;
    f32x4* __restrict__ out4 = reinterpret_cast<f32x4*>(out);

    if (c < NB) {
        const float* oh = reinterpret_cast<const float*>(oh4);
        float v[RPB];
#pragma unroll
        for (int r = 0; r < RPB; ++r) v[r] = oh[(row0 + r) * NB + c];
#pragma unroll
        for (int r = 0; r < RPB; ++r) {
            f32x4* orow = out4 + (size_t)(c * L + row0 + r) * (L / 4);
            const f32x4 v4 = {v[r], v[r], v[r], v[r]};
#pragma unroll
            for (int k = 0; k < 4; ++k)
                __builtin_nontemporal_store(v4, &orow[t + 256 * k]);
        }
    } else {
        const int cc = c - NB;
        // stage column cc once per block with coalesced float4 loads
#pragma unroll
        for (int k = 0; k < 16; ++k) {
            const int p = t + 256 * k;
            const f32x4 w = oh4[p];              // 16 B/lane, lane-consecutive
            col[p] = w[cc];
        }
        __syncthreads();
        const f32x4* col4 = reinterpret_cast<const f32x4*>(col);
        f32x4 v[4];
#pragma unroll
        for (int k = 0; k < 4; ++k) v[k] = col4[t + 256 * k];  // 4 ds_read_b128
#pragma unroll
        for (int r = 0; r < RPB; ++r) {
            f32x4* orow = out4 + (size_t)(c * L + row0 + r) * (L / 4);
#pragma unroll
            for (int k = 0; k < 4; ++k)
                __builtin_nontemporal_store(v[k], &orow[t + 256 * k]);
        }
    }
}

extern "C" void kernel_launch(void* const* d_in, const int* in_sizes, int n_in,
                              void* d_out, int out_size, void* d_ws, size_t ws_size,
                              hipStream_t stream) {
    const f32x4* oh4 = (const f32x4*)d_in[0];
    float* out = (float*)d_out;
    seq_embed<<<8 * BPC, 256, 0, stream>>>(oh4, out);
}